// Round 4
// baseline (508.379 us; speedup 1.0000x reference)
//
#include <hip/hip_runtime.h>
#include <hip/hip_bf16.h>

typedef __attribute__((ext_vector_type(8))) short short8;
typedef __attribute__((ext_vector_type(4))) short short4v;
typedef __attribute__((ext_vector_type(4))) float f32x4;
typedef __attribute__((ext_vector_type(2))) uint uint2v;

constexpr int Bc = 4, Hc = 16, Sc = 2048, Dc = 128;
constexpr int QT = 64;   // q rows per block (4 waves x 16)
constexpr int KT = 64;   // kv columns per tile
constexpr float SCALE_LOG2E = 0.08838834764831845f * 1.4426950408889634f;

__device__ inline ushort bf16r(float x) {
  __hip_bfloat16 h = __float2bfloat16(x);
  return *reinterpret_cast<ushort*>(&h);
}

#define TRRD(dst, o) \
  asm volatile("ds_read_b64_tr_b16 %0, %1 offset:" o : "=v"(dst) : "v"(ybase))
#define TR4(T, o0, o1, o2, o3) \
  TRRD(T[0], o0); TRRD(T[1], o1); TRRD(T[2], o2); TRRD(T[3], o3);
#define WAITL4 asm volatile("s_waitcnt lgkmcnt(4)" ::: "memory"); \
  __builtin_amdgcn_sched_barrier(0)
#define WAITL0 asm volatile("s_waitcnt lgkmcnt(0)" ::: "memory"); \
  __builtin_amdgcn_sched_barrier(0)
#define MM2(dt, T) { \
  short8 b1 = __builtin_shufflevector(T[0], T[1], 0,1,2,3,4,5,6,7); \
  short8 b2 = __builtin_shufflevector(T[2], T[3], 0,1,2,3,4,5,6,7); \
  o_acc[dt] = __builtin_amdgcn_mfma_f32_16x16x32_bf16(ap1, b1, o_acc[dt], 0,0,0); \
  o_acc[dt] = __builtin_amdgcn_mfma_f32_16x16x32_bf16(ap2, b2, o_acc[dt], 0,0,0); }

__global__ __launch_bounds__(256, 2)
void attn_fwd_kernel(const float* __restrict__ Qg, const float* __restrict__ Kg,
                     const float* __restrict__ Vg, const int* __restrict__ padg,
                     float* __restrict__ Og) {
  const int bh = blockIdx.y;
  const int b  = bh >> 4;                       // H = 16
  const int qt = (int)gridDim.x - 1 - (int)blockIdx.x;  // longest first (LPT)
  const int tid = threadIdx.x;
  const int wid = tid >> 6;
  const int lane = tid & 63;
  const int lg = lane >> 4;
  const int lr = lane & 15;

  const size_t base = (size_t)bh * Sc * Dc;
  const float* Qb = Qg + base;
  const float* Kb = Kg + base;
  const float* Vb = Vg + base;
  const int* padb = padg + b * Sc;

  __shared__ ushort K_lds[64 * 128];            // 16KB, swizzled 256B rows
  __shared__ __align__(128) ushort Y_lds[8 * 16 * 64]; // 16KB [dsub8][ksub16][4][16]
  __shared__ ushort P_lds[4][16][72];           // 9.2KB, 144B rows

  const int q0 = qt * QT + wid * 16;

  // Q fragments: lane holds Q[q0+lr][c*32 + lg*8 + i] as bf16
  short8 aq[4];
  #pragma unroll
  for (int c = 0; c < 4; ++c) {
    const float* gq = Qb + (size_t)(q0 + lr) * Dc + c * 32 + lg * 8;
    f32x4 qa = *reinterpret_cast<const f32x4*>(gq);
    f32x4 qc = *reinterpret_cast<const f32x4*>(gq + 4);
    short8 t;
    #pragma unroll
    for (int j = 0; j < 4; ++j) { t[j] = (short)bf16r(qa[j]); t[4+j] = (short)bf16r(qc[j]); }
    aq[c] = t;
  }

  f32x4 o_acc[8];
  #pragma unroll
  for (int i = 0; i < 8; ++i) o_acc[i] = {0.f, 0.f, 0.f, 0.f};
  float m_run[4], l_run[4];
  #pragma unroll
  for (int r = 0; r < 4; ++r) { m_run[r] = -__builtin_inff(); l_run[r] = 0.f; }

  // per-lane QK constants: this lane's k indices are kv0 + beta + j (j=0..3)
  const int beta = ((lr >> 3) & 1) * 32 + (lr & 1) * 16 + ((lr >> 1) & 3) * 4;
  const int kkey = (beta >> 2) & 7;             // K_lds slot-XOR key for rows beta+j

  // staging coords: thread stages row sr, d-quarter dq (32 d's)
  const int sr = tid >> 2;
  const int dq = tid & 3;
  const int skey = (sr >> 2) & 7;

  const uint ybase = (uint)(size_t)(&Y_lds[0]) + (uint)((lg << 7) + (lr << 3));

  // prologue: prefetch tile 0
  f32x4 kreg[8], vreg[8];
  int curp[4], nxtp[4];
  {
    const float* gk = Kb + (size_t)sr * Dc + dq * 32;
    const float* gv = Vb + (size_t)sr * Dc + dq * 32;
    #pragma unroll
    for (int j = 0; j < 8; ++j) {
      kreg[j] = *reinterpret_cast<const f32x4*>(gk + j * 4);
      vreg[j] = *reinterpret_cast<const f32x4*>(gv + j * 4);
    }
    #pragma unroll
    for (int j = 0; j < 4; ++j) { curp[j] = padb[beta + j]; nxtp[j] = curp[j]; }
  }

  const int kv_end = qt * QT + QT;
  for (int kv0 = 0; kv0 < kv_end; kv0 += KT) {
    // barrier A: everyone done reading prev tile's LDS; no vmcnt drain
    asm volatile("" ::: "memory");
    __builtin_amdgcn_s_barrier();
    asm volatile("" ::: "memory");

    // ---- stage K (swizzled) and V (Y subtiles) from prefetched regs ----
    {
      ushort kb[16];
      #pragma unroll
      for (int u = 0; u < 4; ++u)
        #pragma unroll
        for (int j = 0; j < 4; ++j) kb[u * 4 + j] = bf16r(kreg[u][j]);
      #pragma unroll
      for (int u = 0; u < 2; ++u) {
        const int slot = dq * 4 + u;            // covers d = slot*8..slot*8+7
        ushort* kp = &K_lds[sr * 128 + ((slot ^ skey) << 3)];
        *reinterpret_cast<short8*>(kp) = *reinterpret_cast<const short8*>(&kb[u * 8]);
      }
      #pragma unroll
      for (int u = 0; u < 4; ++u)
        #pragma unroll
        for (int j = 0; j < 4; ++j) kb[u * 4 + j] = bf16r(kreg[4 + u][j]);
      #pragma unroll
      for (int u = 0; u < 2; ++u) {
        const int slot = dq * 4 + 2 + u;
        ushort* kp = &K_lds[sr * 128 + ((slot ^ skey) << 3)];
        *reinterpret_cast<short8*>(kp) = *reinterpret_cast<const short8*>(&kb[u * 8]);
      }
      // V -> Y: [dsub][ksub=sr>>2][k&3=sr&3][d&15]
      ushort vb[16];
      #pragma unroll
      for (int h = 0; h < 2; ++h) {
        #pragma unroll
        for (int u = 0; u < 4; ++u)
          #pragma unroll
          for (int j = 0; j < 4; ++j) vb[u * 4 + j] = bf16r(vreg[h * 4 + u][j]);
        ushort* yp = &Y_lds[(2 * dq + h) * 1024 + (sr >> 2) * 64 + (sr & 3) * 16];
        *reinterpret_cast<short8*>(yp)     = *reinterpret_cast<const short8*>(&vb[0]);
        *reinterpret_cast<short8*>(yp + 8) = *reinterpret_cast<const short8*>(&vb[8]);
      }
    }

    // ---- issue next tile's loads (stay in flight across barrier B) ----
    if (kv0 + KT < kv_end) {
      const float* gk = Kb + (size_t)(kv0 + KT + sr) * Dc + dq * 32;
      const float* gv = Vb + (size_t)(kv0 + KT + sr) * Dc + dq * 32;
      #pragma unroll
      for (int j = 0; j < 8; ++j) {
        kreg[j] = *reinterpret_cast<const f32x4*>(gk + j * 4);
        vreg[j] = *reinterpret_cast<const f32x4*>(gv + j * 4);
      }
      #pragma unroll
      for (int j = 0; j < 4; ++j) nxtp[j] = padb[kv0 + KT + beta + j];
    }

    // barrier B: LDS writes visible; vmcnt NOT drained
    asm volatile("s_waitcnt lgkmcnt(0)" ::: "memory");
    __builtin_amdgcn_s_barrier();
    asm volatile("" ::: "memory");

    // ---- QK^T: 4 k-subgroups, lane's k = kv0 + beta + j ----
    f32x4 sj[4];
    #pragma unroll
    for (int j = 0; j < 4; ++j) sj[j] = {0.f, 0.f, 0.f, 0.f};
    #pragma unroll
    for (int c = 0; c < 4; ++c) {
      #pragma unroll
      for (int j = 0; j < 4; ++j) {
        const ushort* kp = &K_lds[(beta + j) * 128 + (((c * 4 + lg) ^ kkey) << 3)];
        short8 bk = *reinterpret_cast<const short8*>(kp);
        sj[j] = __builtin_amdgcn_mfma_f32_16x16x32_bf16(aq[c], bk, sj[j], 0, 0, 0);
      }
    }

    // ---- masked online softmax ----
    float t[4][4], pm[4];
    #pragma unroll
    for (int j = 0; j < 4; ++j) {
      const int ki = kv0 + beta + j;
      #pragma unroll
      for (int r = 0; r < 4; ++r) {
        const int qi = q0 + lg * 4 + r;
        t[j][r] = (ki <= qi && curp[j]) ? sj[j][r] * SCALE_LOG2E : -__builtin_inff();
      }
    }
    #pragma unroll
    for (int r = 0; r < 4; ++r)
      pm[r] = fmaxf(fmaxf(t[0][r], t[1][r]), fmaxf(t[2][r], t[3][r]));
    #pragma unroll
    for (int off = 1; off < 16; off <<= 1)
      #pragma unroll
      for (int r = 0; r < 4; ++r)
        pm[r] = fmaxf(pm[r], __shfl_xor(pm[r], off, 64));

    float al[4], ps[4];
    #pragma unroll
    for (int r = 0; r < 4; ++r) {
      const float mn = fmaxf(m_run[r], pm[r]);
      al[r] = exp2f(m_run[r] - mn);
      float p0 = exp2f(t[0][r] - mn), p1 = exp2f(t[1][r] - mn);
      float p2 = exp2f(t[2][r] - mn), p3 = exp2f(t[3][r] - mn);
      ps[r] = (p0 + p1) + (p2 + p3);
      m_run[r] = mn;
      uint2v w;
      w[0] = (uint)bf16r(p0) | ((uint)bf16r(p1) << 16);
      w[1] = (uint)bf16r(p2) | ((uint)bf16r(p3) << 16);
      *reinterpret_cast<uint2v*>(&P_lds[wid][lg * 4 + r][4 * lr]) = w;  // cols 4lr..4lr+3
    }
    #pragma unroll
    for (int off = 1; off < 16; off <<= 1)
      #pragma unroll
      for (int r = 0; r < 4; ++r)
        ps[r] += __shfl_xor(ps[r], off, 64);
    #pragma unroll
    for (int r = 0; r < 4; ++r) l_run[r] = l_run[r] * al[r] + ps[r];

    #pragma unroll
    for (int dt = 0; dt < 8; ++dt)
      #pragma unroll
      for (int r = 0; r < 4; ++r) o_acc[dt][r] *= al[r];

    // ---- PV: pipelined tr-reads + MFMA ----
    short8 ap1 = *reinterpret_cast<const short8*>(&P_lds[wid][lr][lg * 8]);
    short8 ap2 = *reinterpret_cast<const short8*>(&P_lds[wid][lr][32 + lg * 8]);
    asm volatile("s_waitcnt lgkmcnt(0)" ::: "memory");  // drain: exact counts below
    __builtin_amdgcn_sched_barrier(0);
    short4v ta[4], tb[4];
    TR4(ta, "0", "512", "1024", "1536");
    TR4(tb, "2048", "2560", "3072", "3584");   WAITL4; MM2(0, ta);
    TR4(ta, "4096", "4608", "5120", "5632");   WAITL4; MM2(1, tb);
    TR4(tb, "6144", "6656", "7168", "7680");   WAITL4; MM2(2, ta);
    TR4(ta, "8192", "8704", "9216", "9728");   WAITL4; MM2(3, tb);
    TR4(tb, "10240", "10752", "11264", "11776"); WAITL4; MM2(4, ta);
    TR4(ta, "12288", "12800", "13312", "13824"); WAITL4; MM2(5, tb);
    TR4(tb, "14336", "14848", "15360", "15872"); WAITL4; MM2(6, ta);
    WAITL0; MM2(7, tb);

    #pragma unroll
    for (int j = 0; j < 4; ++j) curp[j] = nxtp[j];
  }

  // epilogue
  float inv[4];
  #pragma unroll
  for (int r = 0; r < 4; ++r) inv[r] = 1.f / l_run[r];
  #pragma unroll
  for (int dt = 0; dt < 8; ++dt) {
    #pragma unroll
    for (int r = 0; r < 4; ++r) {
      const int qi = q0 + lg * 4 + r;
      Og[base + (size_t)qi * Dc + dt * 16 + lr] = o_acc[dt][r] * inv[r];
    }
  }
}

extern "C" void kernel_launch(void* const* d_in, const int* in_sizes, int n_in,
                              void* d_out, int out_size, void* d_ws, size_t ws_size,
                              hipStream_t stream) {
  const float* q = (const float*)d_in[0];
  const float* k = (const float*)d_in[1];
  const float* v = (const float*)d_in[2];
  // d_in[3] = attn_mask (S x S tril) — implemented structurally via k<=q
  const int* pad = (const int*)d_in[4];
  float* out = (float*)d_out;
  dim3 grid(Sc / QT, Bc * Hc);
  attn_fwd_kernel<<<grid, dim3(256), 0, stream>>>(q, k, v, pad, out);
}

// Round 5
// 370.151 us; speedup vs baseline: 1.3734x; 1.3734x over previous
//
#include <hip/hip_runtime.h>
#include <hip/hip_bf16.h>

typedef __attribute__((ext_vector_type(8))) short short8;
typedef __attribute__((ext_vector_type(4))) short short4v;
typedef __attribute__((ext_vector_type(4))) float f32x4;
typedef __attribute__((ext_vector_type(2))) uint uint2v;

constexpr int Bc = 4, Hc = 16, Sc = 2048, Dc = 128;
constexpr int QT = 64;   // q rows per block (4 waves x 16)
constexpr int KT = 64;   // kv columns per tile
constexpr float SCALE_LOG2E = 0.08838834764831845f * 1.4426950408889634f;

__device__ inline ushort bf16r(float x) {
  __hip_bfloat16 h = __float2bfloat16(x);
  return *reinterpret_cast<ushort*>(&h);
}
// lane-xor reduce helpers: xor1/xor2 at VALU speed (DPP quad_perm), xor4/xor8 via ds_swizzle
__device__ inline float qp_xor1(float x) {
  return __int_as_float(__builtin_amdgcn_mov_dpp(__float_as_int(x), 0xB1, 0xF, 0xF, true));
}
__device__ inline float qp_xor2(float x) {
  return __int_as_float(__builtin_amdgcn_mov_dpp(__float_as_int(x), 0x4E, 0xF, 0xF, true));
}
__device__ inline float sw_xor4(float x) {
  return __int_as_float(__builtin_amdgcn_ds_swizzle(__float_as_int(x), 0x101F));
}
__device__ inline float sw_xor8(float x) {
  return __int_as_float(__builtin_amdgcn_ds_swizzle(__float_as_int(x), 0x201F));
}

#define TRRD(dst, o) \
  asm volatile("ds_read_b64_tr_b16 %0, %1 offset:" o : "=v"(dst) : "v"(ycur))
#define TR4(T, o0, o1, o2, o3) \
  TRRD(T[0], o0); TRRD(T[1], o1); TRRD(T[2], o2); TRRD(T[3], o3);
#define WAITL8 asm volatile("s_waitcnt lgkmcnt(8)" ::: "memory"); \
  __builtin_amdgcn_sched_barrier(0)
#define WAITL4 asm volatile("s_waitcnt lgkmcnt(4)" ::: "memory"); \
  __builtin_amdgcn_sched_barrier(0)
#define WAITL0 asm volatile("s_waitcnt lgkmcnt(0)" ::: "memory"); \
  __builtin_amdgcn_sched_barrier(0)
#define MM2(dt, T) { \
  short8 b1 = __builtin_shufflevector(T[0], T[1], 0,1,2,3,4,5,6,7); \
  short8 b2 = __builtin_shufflevector(T[2], T[3], 0,1,2,3,4,5,6,7); \
  o_acc[dt] = __builtin_amdgcn_mfma_f32_16x16x32_bf16(ap1, b1, o_acc[dt], 0,0,0); \
  o_acc[dt] = __builtin_amdgcn_mfma_f32_16x16x32_bf16(ap2, b2, o_acc[dt], 0,0,0); }

__global__ __launch_bounds__(256, 2)
void attn_fwd_kernel(const float* __restrict__ Qg, const float* __restrict__ Kg,
                     const float* __restrict__ Vg, const int* __restrict__ padg,
                     float* __restrict__ Og) {
  // XCD-grouped decode: each XCD (id&7) owns 8 consecutive bh; LPT within
  const int id = blockIdx.x;
  const int qq = id >> 3;
  const int bh = (id & 7) * 8 + (qq >> 5);
  const int qt = 31 - (qq & 31);
  const int b  = bh >> 4;                       // H = 16
  const int tid = threadIdx.x;
  const int wid = tid >> 6;
  const int lane = tid & 63;
  const int lg = lane >> 4;
  const int lr = lane & 15;

  const size_t base = (size_t)bh * Sc * Dc;
  const float* Qb = Qg + base;
  const float* Kb = Kg + base;
  const float* Vb = Vg + base;
  const int* padb = padg + b * Sc;

  __shared__ ushort K_lds[2 * 8192];                 // 2x 64x128 bf16, swizzled 256B rows
  __shared__ __align__(128) ushort Y_lds[2 * 8192];  // 2x V subtiled [dsub8][ksub16][4][16]
  __shared__ ushort P_lds[4][16][72];                // per-wave P, 144B rows

  const int q0 = qt * QT + wid * 16;

  // Q fragments: lane holds Q[q0+lr][c*32 + lg*8 + i] as bf16
  short8 aq[4];
  #pragma unroll
  for (int c = 0; c < 4; ++c) {
    const float* gq = Qb + (size_t)(q0 + lr) * Dc + c * 32 + lg * 8;
    f32x4 qa = *reinterpret_cast<const f32x4*>(gq);
    f32x4 qc = *reinterpret_cast<const f32x4*>(gq + 4);
    short8 t;
    #pragma unroll
    for (int j = 0; j < 4; ++j) { t[j] = (short)bf16r(qa[j]); t[4+j] = (short)bf16r(qc[j]); }
    aq[c] = t;
  }

  f32x4 o_acc[8];
  #pragma unroll
  for (int i = 0; i < 8; ++i) o_acc[i] = {0.f, 0.f, 0.f, 0.f};
  f32x4 o_l = {0.f, 0.f, 0.f, 0.f};                  // row-sum accumulator (denominator)
  float m_run[4];
  #pragma unroll
  for (int r = 0; r < 4; ++r) m_run[r] = -__builtin_inff();

  const short8 aones = { (short)0x3F80, (short)0x3F80, (short)0x3F80, (short)0x3F80,
                         (short)0x3F80, (short)0x3F80, (short)0x3F80, (short)0x3F80 };

  // lane's QK k-indices: kv0 + beta + j
  const int beta = ((lr >> 3) & 1) * 32 + (lr & 1) * 16 + ((lr >> 1) & 3) * 4;
  const int kkey = (beta >> 2) & 7;
  // staging coords
  const int sr = tid >> 2;
  const int dq = tid & 3;
  const int skey = (sr >> 2) & 7;
  const uint ybase = (uint)(size_t)(&Y_lds[0]) + (uint)((lg << 7) + (lr << 3));

  const int ntiles = qt + 1;
  f32x4 kreg[8], vreg[8];
  int pc[4], pn[4];

  auto LOADT = [&](int kv0) {
    const float* gk = Kb + (size_t)(kv0 + sr) * Dc + dq * 32;
    const float* gv = Vb + (size_t)(kv0 + sr) * Dc + dq * 32;
    #pragma unroll
    for (int j = 0; j < 8; ++j) {
      kreg[j] = *reinterpret_cast<const f32x4*>(gk + j * 4);
      vreg[j] = *reinterpret_cast<const f32x4*>(gv + j * 4);
    }
  };
  auto STAGE = [&](int dst) {
    ushort* Kp = &K_lds[dst * 8192];
    ushort* Yp = &Y_lds[dst * 8192];
    ushort kb[16];
    #pragma unroll
    for (int u = 0; u < 4; ++u)
      #pragma unroll
      for (int j = 0; j < 4; ++j) kb[u * 4 + j] = bf16r(kreg[u][j]);
    #pragma unroll
    for (int u = 0; u < 2; ++u) {
      const int slot = dq * 4 + u;
      *reinterpret_cast<short8*>(&Kp[sr * 128 + ((slot ^ skey) << 3)]) =
          *reinterpret_cast<const short8*>(&kb[u * 8]);
    }
    #pragma unroll
    for (int u = 0; u < 4; ++u)
      #pragma unroll
      for (int j = 0; j < 4; ++j) kb[u * 4 + j] = bf16r(kreg[4 + u][j]);
    #pragma unroll
    for (int u = 0; u < 2; ++u) {
      const int slot = dq * 4 + 2 + u;
      *reinterpret_cast<short8*>(&Kp[sr * 128 + ((slot ^ skey) << 3)]) =
          *reinterpret_cast<const short8*>(&kb[u * 8]);
    }
    ushort vb[16];
    #pragma unroll
    for (int h = 0; h < 2; ++h) {
      #pragma unroll
      for (int u = 0; u < 4; ++u)
        #pragma unroll
        for (int j = 0; j < 4; ++j) vb[u * 4 + j] = bf16r(vreg[h * 4 + u][j]);
      ushort* yp = &Yp[(2 * dq + h) * 1024 + (sr >> 2) * 64 + (sr & 3) * 16];
      *reinterpret_cast<short8*>(yp)     = *reinterpret_cast<const short8*>(&vb[0]);
      *reinterpret_cast<short8*>(yp + 8) = *reinterpret_cast<const short8*>(&vb[8]);
    }
  };

  // prologue: tile0 -> buf0; tile1 loads in flight
  LOADT(0);
  #pragma unroll
  for (int j = 0; j < 4; ++j) pc[j] = padb[beta + j];
  STAGE(0);
  if (ntiles > 1) {
    LOADT(KT);
    #pragma unroll
    for (int j = 0; j < 4; ++j) pn[j] = padb[KT + beta + j];
  } else {
    #pragma unroll
    for (int j = 0; j < 4; ++j) pn[j] = pc[j];
  }
  asm volatile("s_waitcnt lgkmcnt(0)" ::: "memory");
  __builtin_amdgcn_s_barrier();

  int cur = 0;
  for (int t = 0; t < ntiles; ++t) {
    const int kv0 = t * KT;
    const ushort* Kc = &K_lds[cur * 8192];
    const uint ycur = ybase + (uint)(cur * 16384);

    // ---- QK^T from buf[cur] ----
    f32x4 sj[4];
    #pragma unroll
    for (int j = 0; j < 4; ++j) sj[j] = {0.f, 0.f, 0.f, 0.f};
    #pragma unroll
    for (int c = 0; c < 4; ++c) {
      #pragma unroll
      for (int j = 0; j < 4; ++j) {
        short8 bk = *reinterpret_cast<const short8*>(
            &Kc[(beta + j) * 128 + (((c * 4 + lg) ^ kkey) << 3)]);
        sj[j] = __builtin_amdgcn_mfma_f32_16x16x32_bf16(aq[c], bk, sj[j], 0, 0, 0);
      }
    }

    // ---- stage t+1 into buf[cur^1]; then issue loads for t+2 ----
    if (t + 1 < ntiles) STAGE(cur ^ 1);
    if (t + 2 < ntiles) LOADT(kv0 + 2 * KT);

    // ---- masked online softmax (max only; sum via MFMA below) ----
    float tt[4][4], pm[4];
    #pragma unroll
    for (int j = 0; j < 4; ++j) {
      const int ki = kv0 + beta + j;
      #pragma unroll
      for (int r = 0; r < 4; ++r) {
        const int qi = q0 + lg * 4 + r;
        tt[j][r] = (ki <= qi && pc[j]) ? sj[j][r] * SCALE_LOG2E : -__builtin_inff();
      }
    }
    #pragma unroll
    for (int r = 0; r < 4; ++r)
      pm[r] = fmaxf(fmaxf(tt[0][r], tt[1][r]), fmaxf(tt[2][r], tt[3][r]));
    #pragma unroll
    for (int r = 0; r < 4; ++r) {
      pm[r] = fmaxf(pm[r], qp_xor1(pm[r]));
      pm[r] = fmaxf(pm[r], qp_xor2(pm[r]));
    }
    #pragma unroll
    for (int r = 0; r < 4; ++r) pm[r] = fmaxf(pm[r], sw_xor4(pm[r]));
    #pragma unroll
    for (int r = 0; r < 4; ++r) pm[r] = fmaxf(pm[r], sw_xor8(pm[r]));

    float al[4];
    #pragma unroll
    for (int r = 0; r < 4; ++r) {
      const float mn = fmaxf(m_run[r], pm[r]);
      al[r] = exp2f(m_run[r] - mn);
      const float p0 = exp2f(tt[0][r] - mn), p1 = exp2f(tt[1][r] - mn);
      const float p2 = exp2f(tt[2][r] - mn), p3 = exp2f(tt[3][r] - mn);
      m_run[r] = mn;
      uint2v w;
      w[0] = (uint)bf16r(p0) | ((uint)bf16r(p1) << 16);
      w[1] = (uint)bf16r(p2) | ((uint)bf16r(p3) << 16);
      *reinterpret_cast<uint2v*>(&P_lds[wid][lg * 4 + r][4 * lr]) = w;
    }

    // pad pipeline shift + issue next pad loads (clamped; harmless if unused)
    #pragma unroll
    for (int j = 0; j < 4; ++j) pc[j] = pn[j];
    {
      const int nb = (kv0 + 2 * KT < Sc) ? kv0 + 2 * KT : Sc - KT;
      #pragma unroll
      for (int j = 0; j < 4; ++j) pn[j] = padb[nb + beta + j];
    }

    // ---- PV: counted-wait pipeline (ap reads + tr-read quads + MFMAs) ----
    WAITL0;  // drain stage/P writes + swizzles: counts below are exact
    short8 ap1 = *reinterpret_cast<const short8*>(&P_lds[wid][lr][lg * 8]);
    short8 ap2 = *reinterpret_cast<const short8*>(&P_lds[wid][lr][32 + lg * 8]);
    short4v ta[4], tb[4];
    TR4(ta, "0", "512", "1024", "1536");
    TR4(tb, "2048", "2560", "3072", "3584");
    // rescale under ap/tr latency
    #pragma unroll
    for (int dt = 0; dt < 8; ++dt)
      #pragma unroll
      for (int r = 0; r < 4; ++r) o_acc[dt][r] *= al[r];
    #pragma unroll
    for (int r = 0; r < 4; ++r) o_l[r] *= al[r];
    WAITL8;  // ap1, ap2 ready
    o_l = __builtin_amdgcn_mfma_f32_16x16x32_bf16(ap1, aones, o_l, 0, 0, 0);
    o_l = __builtin_amdgcn_mfma_f32_16x16x32_bf16(ap2, aones, o_l, 0, 0, 0);
    WAITL4; MM2(0, ta);
    TR4(ta, "4096", "4608", "5120", "5632");
    WAITL4; MM2(1, tb);
    TR4(tb, "6144", "6656", "7168", "7680");
    WAITL4; MM2(2, ta);
    TR4(ta, "8192", "8704", "9216", "9728");
    WAITL4; MM2(3, tb);
    TR4(tb, "10240", "10752", "11264", "11776");
    WAITL4; MM2(4, ta);
    TR4(ta, "12288", "12800", "13312", "13824");
    WAITL4; MM2(5, tb);
    TR4(tb, "14336", "14848", "15360", "15872");
    WAITL4; MM2(6, ta);
    WAITL0; MM2(7, tb);

    // single barrier per tile; vmcnt NOT drained (t+2 loads stay in flight)
    asm volatile("s_waitcnt lgkmcnt(0)" ::: "memory");
    __builtin_amdgcn_s_barrier();
    cur ^= 1;
  }

  // epilogue
  float inv[4];
  #pragma unroll
  for (int r = 0; r < 4; ++r) inv[r] = 1.f / o_l[r];
  #pragma unroll
  for (int dt = 0; dt < 8; ++dt) {
    #pragma unroll
    for (int r = 0; r < 4; ++r) {
      const int qi = q0 + lg * 4 + r;
      Og[base + (size_t)qi * Dc + dt * 16 + lr] = o_acc[dt][r] * inv[r];
    }
  }
}

extern "C" void kernel_launch(void* const* d_in, const int* in_sizes, int n_in,
                              void* d_out, int out_size, void* d_ws, size_t ws_size,
                              hipStream_t stream) {
  const float* q = (const float*)d_in[0];
  const float* k = (const float*)d_in[1];
  const float* v = (const float*)d_in[2];
  // d_in[3] = attn_mask (S x S tril) — implemented structurally via k<=q
  const int* pad = (const int*)d_in[4];
  float* out = (float*)d_out;
  attn_fwd_kernel<<<dim3(Sc / QT * Bc * Hc), dim3(256), 0, stream>>>(q, k, v, pad, out);
}